// Round 11
// baseline (396.336 us; speedup 1.0000x reference)
//
#include <hip/hip_runtime.h>

typedef short bf16x8 __attribute__((ext_vector_type(8)));
typedef float f32x4 __attribute__((ext_vector_type(4)));
typedef unsigned long long u64;

#define N_NODES 4096
#define N_EDGES 16384
#define FN 128
#define FE 64
#define NJS 16
#define EJS 32

#define PACKE_BLOCKS 1024   // 256 jt x 4 i-quarters
#define PACKN_BLOCKS 256    // 64 jt x 4 i-quarters
#define EPROJ_BLOCKS (N_EDGES / 4)    // 4096
#define NPROJ_BLOCKS (N_NODES / 4)    // 1024
#define PREPE_BLOCKS (N_EDGES / 32)   // 512
#define PREPN_BLOCKS (N_NODES / 32)   // 128
#define FRONT_BLOCKS (PACKE_BLOCKS + PACKN_BLOCKS + EPROJ_BLOCKS + NPROJ_BLOCKS + PREPE_BLOCKS + PREPN_BLOCKS)

#define ATTN_BLOCKS (32 * NJS)    // 512
#define ATTE_BLOCKS (32 * EJS)    // 1024

__device__ __forceinline__ float lrelu(float x) { return x >= 0.f ? x : 0.01f * x; }
__device__ __forceinline__ unsigned short f2bf(float f) {
    unsigned int x = __float_as_uint(f);
    return (unsigned short)((x + 0x7fffu + ((x >> 16) & 1u)) >> 16);
}
// order-preserving float->u32 encoding (for atomicMax); memset-0 == -inf
__device__ __forceinline__ unsigned encf(float x) {
    unsigned b = __float_as_uint(x);
    return (b >> 31) ? ~b : (b | 0x80000000u);
}
__device__ __forceinline__ float decf(unsigned e) {
    return __uint_as_float((e & 0x80000000u) ? (e ^ 0x80000000u) : ~e);
}

// ---- prep (32-row tiles): src[j][f] f32 -> dst[j/8][F][8] bf16 ----
__device__ __forceinline__ void prep_b32(
    const float* __restrict__ src, unsigned short* __restrict__ dst,
    int j0, int F, int lf, float* tile /* [32][F+1] */) {
    const int t = threadIdx.x;
    const int P = F + 1;
    const int LITERS = (32 * F) >> 10;
    for (int it = 0; it < LITERS; ++it) {
        int idx = (it * 256 + t) * 4;
        int j = idx >> lf, f = idx & (F - 1);
        float4 v = *(const float4*)(src + (size_t)(j0 + j) * F + f);
        tile[j * P + f + 0] = v.x; tile[j * P + f + 1] = v.y;
        tile[j * P + f + 2] = v.z; tile[j * P + f + 3] = v.w;
    }
    __syncthreads();
    const int WITERS = (32 * F) >> 11;
    for (int it = 0; it < WITERS; ++it) {
        int c = it * 256 + t;
        int jo = c >> lf, f = c & (F - 1);
        bf16x8 v;
#pragma unroll
        for (int e = 0; e < 8; ++e) v[e] = (short)f2bf(tile[(jo * 8 + e) * P + f]);
        *(bf16x8*)(dst + (((size_t)(j0 >> 3) + jo) * F + f) * 8) = v;
    }
}

// ---- pack: 64 j-rows x 1024-i quarter -> mt2[jt][i] u64, all phases coalesced ----
__device__ __forceinline__ void pack_tile(
    const int* __restrict__ src, u64* __restrict__ dst,
    int jt, int iq, unsigned char* lds8 /* [64][260] */) {
    const int t = threadIdx.x;
    const int wv = t >> 6, ln = t & 63;
    const size_t rowbase = (size_t)jt * 64;
    for (int p = 0; p < 4; ++p) {
        const int ib = iq * 1024 + p * 256;
#pragma unroll
        for (int it = 0; it < 16; ++it) {
            int idx = it * 256 + t;
            int row = idx >> 6, c = idx & 63;
            int4 v = *(const int4*)(src + (rowbase + row) * N_NODES + ib + c * 4);
            unsigned bb = (unsigned)(v.x > 0) | ((unsigned)(v.y > 0) << 8) |
                          ((unsigned)(v.z > 0) << 16) | ((unsigned)(v.w > 0) << 24);
            *(unsigned*)&lds8[row * 260 + c * 4] = bb;
        }
        __syncthreads();
        u64 myw = 0;
#pragma unroll 16
        for (int q = 0; q < 64; ++q) {
            unsigned char val = lds8[ln * 260 + wv * 64 + q];
            u64 b = __ballot(val != 0);
            if (ln == q) myw = b;
        }
        dst[(size_t)jt * N_NODES + ib + wv * 64 + ln] = myw;
        __syncthreads();
    }
}

// ---- kernel 1 (fused front): coalesced transposing pack + projections (+atomic max) + prep ----
__global__ __launch_bounds__(256) void k_front(
    const float* __restrict__ nf, const float* __restrict__ ef,
    const int* __restrict__ adj, const int* __restrict__ eadj,
    const float* __restrict__ Wn, const float* __restrict__ We,
    const float* __restrict__ pvn, const float* __restrict__ pve,
    u64* __restrict__ mt2N, u64* __restrict__ mt2E,
    float* __restrict__ alpha, float* __restrict__ beta, float* __restrict__ gamma,
    float* __restrict__ betaE, unsigned* __restrict__ maxesU,
    unsigned short* __restrict__ XbN, unsigned short* __restrict__ XbE) {
    __shared__ float smem[4160];   // 16640 B, union across branches
    int bx = blockIdx.x;
    const int t = threadIdx.x;
    const int wv = t >> 6, ln = t & 63;

    if (bx < PACKE_BLOCKS) {
        pack_tile(eadj, mt2E, bx >> 2, bx & 3, (unsigned char*)smem);
        return;
    }
    bx -= PACKE_BLOCKS;
    if (bx < PACKN_BLOCKS) {
        pack_tile(adj, mt2N, bx >> 2, bx & 3, (unsigned char*)smem);
        return;
    }
    bx -= PACKN_BLOCKS;
    if (bx < EPROJ_BLOCKS) {
        float* row = smem;   // [4][FE]
        const int e = bx * 4 + wv;
        row[wv * FE + ln] = ef[(size_t)e * FE + ln];
        __syncthreads();
        float h = 0.f;
#pragma unroll 8
        for (int k = 0; k < FE; ++k)
            h = fmaf(row[wv * FE + k], We[(size_t)k * FE + ln], h);
        float p = h * pve[FN + ln];
#pragma unroll
        for (int off = 32; off > 0; off >>= 1) p += __shfl_down(p, off, 64);
        if (ln == 0) {
            betaE[e] = p;
            atomicMax(&maxesU[1], encf(p));
        }
        return;
    }
    bx -= EPROJ_BLOCKS;
    if (bx < NPROJ_BLOCKS) {
        float* row = smem;   // [4][FN]
        const int i = bx * 4 + wv;
        float2 r2 = *(const float2*)(nf + (size_t)i * FN + ln * 2);
        row[wv * FN + ln * 2] = r2.x; row[wv * FN + ln * 2 + 1] = r2.y;
        __syncthreads();
        float h0 = 0.f, h1 = 0.f;
#pragma unroll 8
        for (int k = 0; k < FN; ++k) {
            float nv = row[wv * FN + k];
            float2 w2 = *(const float2*)(Wn + (size_t)k * FN + ln * 2);
            h0 = fmaf(nv, w2.x, h0); h1 = fmaf(nv, w2.y, h1);
        }
        float2 as = *(const float2*)(pvn + ln * 2);
        float2 an = *(const float2*)(pvn + FN + ln * 2);
        float2 bs = *(const float2*)(pve + ln * 2);
        float pa = h0 * as.x + h1 * as.y;
        float pb = h0 * an.x + h1 * an.y;
        float pg = h0 * bs.x + h1 * bs.y;
#pragma unroll
        for (int off = 32; off > 0; off >>= 1) {
            pa += __shfl_down(pa, off, 64);
            pb += __shfl_down(pb, off, 64);
            pg += __shfl_down(pg, off, 64);
        }
        if (ln == 0) {
            alpha[i] = pa; beta[i] = pb; gamma[i] = pg;
            atomicMax(&maxesU[0], encf(pb));
        }
        return;
    }
    bx -= NPROJ_BLOCKS;
    if (bx < PREPE_BLOCKS) {
        prep_b32(ef, XbE, bx * 32, FE, 6, smem);
        return;
    }
    bx -= PREPE_BLOCKS;
    prep_b32(nf, XbN, bx * 32, FN, 7, smem);
}

// ---- kernel 2: fused attention; mask layout mt2[jt][i] (u32 view) ----
__global__ __launch_bounds__(256) void k_att(
    const unsigned short* __restrict__ XbN, const unsigned short* __restrict__ XbE,
    const unsigned* __restrict__ mtNu, const unsigned* __restrict__ mtEu,
    const float* __restrict__ alpha, const float* __restrict__ beta,
    const float* __restrict__ gamma, const float* __restrict__ betaE,
    const unsigned* __restrict__ maxesU,
    float* __restrict__ accN, float* __restrict__ zN, float* __restrict__ degN,
    float* __restrict__ accE, float* __restrict__ zE, float* __restrict__ degE) {
    const int t = threadIdx.x, l = t & 63, wid = t >> 6;
    const int l15 = l & 15, lq = l >> 4;
    int b = blockIdx.x;
    if (b < ATTN_BLOCKS) {
        // ---------------- node side ----------------
        const int bx = b & 31, bj = b >> 5;
        const int j0 = bj * (N_NODES / NJS);        // 256
        const int i0 = bx * 128 + wid * 32;
        const float a0 = alpha[i0 + l15], a1 = alpha[i0 + 16 + l15];
        const float mx = decf(maxesU[0]);
        const float m0 = lrelu(a0 + mx), m1 = lrelu(a1 + mx);
        const int ib0 = (i0 + l15) * 2, ib1 = (i0 + 16 + l15) * 2;
        f32x4 acc0[8] = {}, acc1[8] = {};
        float z0 = 0.f, z1 = 0.f;
        int d0 = 0, d1 = 0;
        const unsigned short* xb0 = XbN + (((size_t)(j0 >> 3) + lq) * FN + l15) * 8;
        const float* bb0 = beta + j0 + lq * 8;
        for (int ks = 0; ks < (N_NODES / NJS) / 32; ++ks) {   // 8
            const int jb = ks * 32;
            const int widx = ((bj << 2) + (ks >> 1)) * 8192 + (ks & 1);
            unsigned m32a = mtNu[widx + ib0];
            unsigned m32b = mtNu[widx + ib1];
            d0 += __popc((m32a >> (lq * 8)) & 0xffu);
            d1 += __popc((m32b >> (lq * 8)) & 0xffu);
            float4 b0v = *(const float4*)(bb0 + jb);
            float4 b1v = *(const float4*)(bb0 + jb + 4);
            float bv[8] = {b0v.x, b0v.y, b0v.z, b0v.w, b1v.x, b1v.y, b1v.z, b1v.w};
            bf16x8 wf0, wf1;
#pragma unroll
            for (int e = 0; e < 8; ++e) {
                int sh = lq * 8 + e;
                int mka = (int)((m32a >> sh) & 1u);
                int mkb = (int)((m32b >> sh) & 1u);
                float s0 = lrelu(a0 + bv[e]);
                float w0 = mka ? __expf(s0 - m0) : 0.f;
                float s1 = lrelu(a1 + bv[e]);
                float w1 = mkb ? __expf(s1 - m1) : 0.f;
                z0 += w0; z1 += w1;
                wf0[e] = (short)f2bf(w0);
                wf1[e] = (short)f2bf(w1);
            }
            const unsigned short* xa = xb0 + (size_t)(jb >> 3) * (FN * 8);
#pragma unroll
            for (int mi = 0; mi < 8; ++mi) {
                bf16x8 a = *(const bf16x8*)(xa + mi * 128);
                acc0[mi] = __builtin_amdgcn_mfma_f32_16x16x32_bf16(a, wf0, acc0[mi], 0, 0, 0);
                acc1[mi] = __builtin_amdgcn_mfma_f32_16x16x32_bf16(a, wf1, acc1[mi], 0, 0, 0);
            }
        }
        float d0f = (float)d0, d1f = (float)d1;
        z0 += __shfl_xor(z0, 16, 64); z0 += __shfl_xor(z0, 32, 64);
        d0f += __shfl_xor(d0f, 16, 64); d0f += __shfl_xor(d0f, 32, 64);
        z1 += __shfl_xor(z1, 16, 64); z1 += __shfl_xor(z1, 32, 64);
        d1f += __shfl_xor(d1f, 16, 64); d1f += __shfl_xor(d1f, 32, 64);
        if (l < 16) {
            zN[bj * N_NODES + i0 + l] = z0;   degN[bj * N_NODES + i0 + l] = d0f;
            zN[bj * N_NODES + i0 + 16 + l] = z1;   degN[bj * N_NODES + i0 + 16 + l] = d1f;
        }
#pragma unroll
        for (int mi = 0; mi < 8; ++mi) {
            *(f32x4*)(accN + ((size_t)bj * N_NODES + i0 + l15) * FN + mi * 16 + lq * 4) = acc0[mi];
            *(f32x4*)(accN + ((size_t)bj * N_NODES + i0 + 16 + l15) * FN + mi * 16 + lq * 4) = acc1[mi];
        }
    } else {
        // ---------------- edge side ----------------
        b -= ATTN_BLOCKS;
        const int bx = b & 31, bj = b >> 5;
        const int j0 = bj * (N_EDGES / EJS);        // 512
        const int i0 = bx * 128 + wid * 32;
        const float a0 = gamma[i0 + l15], a1 = gamma[i0 + 16 + l15];
        const float mx = decf(maxesU[1]);
        const float m0 = lrelu(a0 + mx), m1 = lrelu(a1 + mx);
        const int ib0 = (i0 + l15) * 2, ib1 = (i0 + 16 + l15) * 2;
        f32x4 acc0[4] = {}, acc1[4] = {};
        float z0 = 0.f, z1 = 0.f;
        int d0 = 0, d1 = 0;
        const unsigned short* xb0 = XbE + (((size_t)(j0 >> 3) + lq) * FE + l15) * 8;
        const float* bb0 = betaE + j0 + lq * 8;
        for (int ks = 0; ks < (N_EDGES / EJS) / 32; ++ks) {   // 16
            const int jb = ks * 32;
            const int widx = ((bj << 3) + (ks >> 1)) * 8192 + (ks & 1);
            unsigned m32a = mtEu[widx + ib0];
            unsigned m32b = mtEu[widx + ib1];
            d0 += __popc((m32a >> (lq * 8)) & 0xffu);
            d1 += __popc((m32b >> (lq * 8)) & 0xffu);
            float4 b0v = *(const float4*)(bb0 + jb);
            float4 b1v = *(const float4*)(bb0 + jb + 4);
            float bv[8] = {b0v.x, b0v.y, b0v.z, b0v.w, b1v.x, b1v.y, b1v.z, b1v.w};
            bf16x8 wf0, wf1;
#pragma unroll
            for (int e = 0; e < 8; ++e) {
                int sh = lq * 8 + e;
                int mka = (int)((m32a >> sh) & 1u);
                int mkb = (int)((m32b >> sh) & 1u);
                float s0 = lrelu(a0 + bv[e]);
                float w0 = mka ? __expf(s0 - m0) : 0.f;
                float s1 = lrelu(a1 + bv[e]);
                float w1 = mkb ? __expf(s1 - m1) : 0.f;
                z0 += w0; z1 += w1;
                wf0[e] = (short)f2bf(w0);
                wf1[e] = (short)f2bf(w1);
            }
            const unsigned short* xa = xb0 + (size_t)(jb >> 3) * (FE * 8);
#pragma unroll
            for (int mi = 0; mi < 4; ++mi) {
                bf16x8 a = *(const bf16x8*)(xa + mi * 128);
                acc0[mi] = __builtin_amdgcn_mfma_f32_16x16x32_bf16(a, wf0, acc0[mi], 0, 0, 0);
                acc1[mi] = __builtin_amdgcn_mfma_f32_16x16x32_bf16(a, wf1, acc1[mi], 0, 0, 0);
            }
        }
        float d0f = (float)d0, d1f = (float)d1;
        z0 += __shfl_xor(z0, 16, 64); z0 += __shfl_xor(z0, 32, 64);
        d0f += __shfl_xor(d0f, 16, 64); d0f += __shfl_xor(d0f, 32, 64);
        z1 += __shfl_xor(z1, 16, 64); z1 += __shfl_xor(z1, 32, 64);
        d1f += __shfl_xor(d1f, 16, 64); d1f += __shfl_xor(d1f, 32, 64);
        if (l < 16) {
            zE[bj * N_NODES + i0 + l] = z0;   degE[bj * N_NODES + i0 + l] = d0f;
            zE[bj * N_NODES + i0 + 16 + l] = z1;   degE[bj * N_NODES + i0 + 16 + l] = d1f;
        }
#pragma unroll
        for (int mi = 0; mi < 4; ++mi) {
            *(f32x4*)(accE + ((size_t)bj * N_NODES + i0 + l15) * FE + mi * 16 + lq * 4) = acc0[mi];
            *(f32x4*)(accE + ((size_t)bj * N_NODES + i0 + 16 + l15) * FE + mi * 16 + lq * 4) = acc1[mi];
        }
    }
}

// ---- kernel 3: fused epilogues ----
__global__ __launch_bounds__(256) void k_out(
    const float* __restrict__ accN, const float* __restrict__ zN, const float* __restrict__ degN,
    const float* __restrict__ accE, const float* __restrict__ zE, const float* __restrict__ degE,
    const float* __restrict__ Wn, const float* __restrict__ We,
    float* __restrict__ out) {
    __shared__ float ml[4][FN];
    const int wv = threadIdx.x >> 6, ln = threadIdx.x & 63;
    int b = blockIdx.x;
    if (b < N_NODES / 4) {
        const int i = b * 4 + wv;
        float s0 = 0.f, s1 = 0.f;
#pragma unroll
        for (int js = 0; js < NJS; ++js) {
            float2 v = *(const float2*)(accN + ((size_t)js * N_NODES + i) * FN + ln * 2);
            s0 += v.x; s1 += v.y;
        }
        float z = 0.f, d = 0.f;
#pragma unroll
        for (int js = 0; js < NJS; ++js) { z += zN[js * N_NODES + i]; d += degN[js * N_NODES + i]; }
        float zd = z * d;
        float inv = zd > 0.f ? 1.f / zd : 0.f;
        ml[wv][ln * 2] = s0 * inv; ml[wv][ln * 2 + 1] = s1 * inv;
        __syncthreads();
        float o0 = 0.f, o1 = 0.f;
#pragma unroll 8
        for (int k = 0; k < FN; ++k) {
            float mvv = ml[wv][k];
            float2 w2 = *(const float2*)(Wn + (size_t)k * FN + ln * 2);
            o0 = fmaf(mvv, w2.x, o0); o1 = fmaf(mvv, w2.y, o1);
        }
        out[(size_t)i * 192 + ln * 2] = lrelu(o0);
        out[(size_t)i * 192 + ln * 2 + 1] = lrelu(o1);
    } else {
        b -= N_NODES / 4;
        const int i = b * 4 + wv;
        float s = 0.f;
#pragma unroll
        for (int js = 0; js < EJS; ++js)
            s += accE[((size_t)js * N_NODES + i) * FE + ln];
        float z = 0.f, d = 0.f;
#pragma unroll
        for (int js = 0; js < EJS; ++js) { z += zE[js * N_NODES + i]; d += degE[js * N_NODES + i]; }
        float zd = z * d;
        float inv = zd > 0.f ? 1.f / zd : 0.f;
        ml[wv][ln] = s * inv;
        __syncthreads();
        float o = 0.f;
#pragma unroll 8
        for (int k = 0; k < FE; ++k)
            o = fmaf(ml[wv][k], We[(size_t)k * FE + ln], o);
        out[(size_t)i * 192 + 128 + ln] = lrelu(o);
    }
}

extern "C" void kernel_launch(void* const* d_in, const int* in_sizes, int n_in,
                              void* d_out, int out_size, void* d_ws, size_t ws_size,
                              hipStream_t stream) {
    (void)in_sizes; (void)n_in; (void)out_size; (void)ws_size;
    const float* nf   = (const float*)d_in[0];
    const float* ef   = (const float*)d_in[1];
    const int*   adj  = (const int*)d_in[2];
    const int*   eadj = (const int*)d_in[3];
    const float* Wn   = (const float*)d_in[4];
    const float* We   = (const float*)d_in[5];
    const float* pvn  = (const float*)d_in[6];
    const float* pve  = (const float*)d_in[7];
    float* out = (float*)d_out;

    u64* mt2N = (u64*)d_ws;                                 // [64][4096]  = 2 MB
    u64* mt2E = mt2N + (size_t)64 * N_NODES;                // [256][4096] = 8 MB
    float* alpha = (float*)(mt2E + (size_t)256 * N_NODES);
    float* beta  = alpha + 4096;
    float* gamma = beta + 4096;
    float* betaE = gamma + 4096;
    unsigned* maxesU = (unsigned*)(betaE + 16384);          // 16 u32 (padded)
    unsigned short* XbN = (unsigned short*)(maxesU + 16);           // 1 MB
    unsigned short* XbE = XbN + (size_t)(N_NODES / 8) * FN * 8;     // 2 MB
    float* accN = (float*)(XbE + (size_t)(N_EDGES / 8) * FE * 8);   // 33.5 MB
    float* zN   = accN + (size_t)NJS * N_NODES * FN;
    float* degN = zN + (size_t)NJS * N_NODES;
    float* accE = degN + (size_t)NJS * N_NODES;                     // 33.5 MB
    float* zE   = accE + (size_t)EJS * N_NODES * FE;
    float* degE = zE + (size_t)EJS * N_NODES;

    hipMemsetAsync(maxesU, 0, 2 * sizeof(unsigned), stream);
    k_front<<<FRONT_BLOCKS, 256, 0, stream>>>(nf, ef, adj, eadj, Wn, We, pvn, pve,
                                              mt2N, mt2E, alpha, beta, gamma, betaE, maxesU, XbN, XbE);
    k_att<<<ATTN_BLOCKS + ATTE_BLOCKS, 256, 0, stream>>>(
        XbN, XbE, (const unsigned*)mt2N, (const unsigned*)mt2E,
        alpha, beta, gamma, betaE, maxesU, accN, zN, degN, accE, zE, degE);
    k_out<<<N_NODES / 4 + N_NODES / 4, 256, 0, stream>>>(
        accN, zN, degN, accE, zE, degE, Wn, We, out);
}